// Round 5
// baseline (422.859 us; speedup 1.0000x reference)
//
#include <hip/hip_runtime.h>

#define N 4096

__device__ __forceinline__ void load_A(const float* __restrict__ Ag,
                                       float Ac[3][3], float& inv)
{
#pragma unroll
    for (int i = 0; i < 9; ++i) Ac[i / 3][i % 3] = Ag[i];
    inv = 1.0f / Ac[1][1];
    Ac[1][1] = 0.f;
}

// Stage a 34x136 u-window into LDS. Row r <-> gy = uy0 + r, col c <-> gx = gxa + c.
// Fast path: aligned float4 loads + b128 LDS writes. Slow path: clamped scalar
// (replicate edges, zero the padded-frame corners).
__device__ __forceinline__ void stage_u_tile(const float* __restrict__ u,
                                             float su[34][136],
                                             int uy0, int gxa, int t)
{
    const int n = N;
    bool safe = (uy0 >= 0) & (uy0 + 34 <= n) & (gxa >= 0) & (gxa + 136 <= n);
    if (safe) {
        const float* ub = &u[(size_t)uy0 * n + gxa];
#pragma unroll
        for (int s = 0; s < 5; ++s) {
            int idx = t + 256 * s;
            if (idx < 34 * 34) {
                int row = idx / 34, k = idx - row * 34;
                float4 v = *(const float4*)&ub[(size_t)row * n + 4 * k];
                *(float4*)&su[row][4 * k] = v;
            }
        }
    } else {
        for (int i = t; i < 34 * 136; i += 256) {
            int row = i / 136, c = i - row * 136;
            int gy = uy0 + row, gx = gxa + c;
            bool oy = (gy < 0) | (gy >= n);
            bool ox = (gx < 0) | (gx >= n);
            int cy = min(max(gy, 0), n - 1), cx = min(max(gx, 0), n - 1);
            su[row][c] = (oy & ox) ? 0.f : u[(size_t)cy * n + cx];
        }
    }
}

// ---- fused smooth(bc(u)) + 2x2 restrict -> r1 (2048^2); tile 64x16 of r1 ----
__global__ __launch_bounds__(256) void smooth_restrict_kernel(
    const float* __restrict__ u, const float* __restrict__ Ag,
    float* __restrict__ r1)
{
    __shared__ __align__(16) float su[34][136];
    int bx = blockIdx.x, by = blockIdx.y, t = threadIdx.x;
    stage_u_tile(u, su, 32 * by - 1, 128 * bx - 4, t);
    float Ac[3][3], inv;
    load_A(Ag, Ac, inv);
    float w[4][4];
#pragma unroll
    for (int a = 0; a < 4; ++a)
#pragma unroll
        for (int b = 0; b < 4; ++b) w[a][b] = 0.f;
#pragma unroll
    for (int r = 0; r < 2; ++r)
#pragma unroll
        for (int c = 0; c < 2; ++c)
#pragma unroll
            for (int i = 0; i < 3; ++i)
#pragma unroll
                for (int j = 0; j < 3; ++j) w[r + i][c + j] += Ac[i][j];
    __syncthreads();

    int tx = t & 31, ty = t >> 5;
#pragma unroll
    for (int rr = 0; rr < 2; ++rr) {
        int yr = ty + 8 * rr;
        float o0 = 0.f, o1 = 0.f;
#pragma unroll
        for (int a = 0; a < 4; ++a) {
            const float* row = su[2 * yr + a];
            float L = row[4 * tx + 3];
            float4 m = *(const float4*)&row[4 * tx + 4];
            float R = row[4 * tx + 8];
            float v[6] = {L, m.x, m.y, m.z, m.w, R};
#pragma unroll
            for (int b = 0; b < 4; ++b) {
                o0 += w[a][b] * v[b];
                o1 += w[a][b] * v[b + 2];
            }
        }
        *(float2*)&r1[(size_t)(16 * by + yr) * 2048 + 64 * bx + 2 * tx] =
            make_float2(0.25f * o0, 0.25f * o1);
    }
}

// ---- one-shot restriction tree: r1 -> r2..r7 ----
__global__ __launch_bounds__(256) void multirestrict_kernel(
    const float* __restrict__ r1, float* __restrict__ r2, float* __restrict__ r3,
    float* __restrict__ r4, float* __restrict__ r5, float* __restrict__ r6,
    float* __restrict__ r7)
{
    const int n1 = 2048, n2 = 1024, n3 = 512, n4 = 256, n5 = 128, n6 = 64, n7 = 32;
    int BX = blockIdx.x, BY = blockIdx.y;
    __shared__ __align__(16) float s2[32][36];
    __shared__ float s3[16][17];
    __shared__ float s4[8][9];
    __shared__ float s5[4][5];
    __shared__ float s6[2][3];
    int t = threadIdx.x;
    {
        int R = t >> 3, c8 = (t & 7) * 8;
        const float* base0 = &r1[(size_t)(BY * 64 + 2 * R) * n1 + BX * 64 + c8];
        const float* base1 = base0 + n1;
        float4 a0 = ((const float4*)base0)[0], a1 = ((const float4*)base0)[1];
        float4 b0 = ((const float4*)base1)[0], b1 = ((const float4*)base1)[1];
        float4 o;
        o.x = 0.25f * (a0.x + a0.y + b0.x + b0.y);
        o.y = 0.25f * (a0.z + a0.w + b0.z + b0.w);
        o.z = 0.25f * (a1.x + a1.y + b1.x + b1.y);
        o.w = 0.25f * (a1.z + a1.w + b1.z + b1.w);
        *(float4*)&r2[(size_t)(BY * 32 + R) * n2 + BX * 32 + (t & 7) * 4] = o;
        *(float4*)&s2[R][(t & 7) * 4] = o;
    }
    __syncthreads();
    {
        int y = t >> 4, x = t & 15;
        float v = 0.25f * (s2[2 * y][2 * x] + s2[2 * y][2 * x + 1] +
                           s2[2 * y + 1][2 * x] + s2[2 * y + 1][2 * x + 1]);
        r3[(size_t)(BY * 16 + y) * n3 + BX * 16 + x] = v;
        s3[y][x] = v;
    }
    __syncthreads();
    if (t < 64) {
        int y = t >> 3, x = t & 7;
        float v = 0.25f * (s3[2 * y][2 * x] + s3[2 * y][2 * x + 1] +
                           s3[2 * y + 1][2 * x] + s3[2 * y + 1][2 * x + 1]);
        r4[(size_t)(BY * 8 + y) * n4 + BX * 8 + x] = v;
        s4[y][x] = v;
    }
    __syncthreads();
    if (t < 16) {
        int y = t >> 2, x = t & 3;
        float v = 0.25f * (s4[2 * y][2 * x] + s4[2 * y][2 * x + 1] +
                           s4[2 * y + 1][2 * x] + s4[2 * y + 1][2 * x + 1]);
        r5[(size_t)(BY * 4 + y) * n5 + BX * 4 + x] = v;
        s5[y][x] = v;
    }
    __syncthreads();
    if (t < 4) {
        int y = t >> 1, x = t & 1;
        float v = 0.25f * (s5[2 * y][2 * x] + s5[2 * y][2 * x + 1] +
                           s5[2 * y + 1][2 * x] + s5[2 * y + 1][2 * x + 1]);
        r6[(size_t)(BY * 2 + y) * n6 + BX * 2 + x] = v;
        s6[y][x] = v;
    }
    __syncthreads();
    if (t == 0) {
        r7[(size_t)BY * n7 + BX] =
            0.25f * (s6[0][0] + s6[0][1] + s6[1][0] + s6[1][1]);
    }
}

// ---- fused coarse up-chain: r7..r3 -> e@512 ----
__global__ __launch_bounds__(256) void coarse_up_kernel(
    const float* __restrict__ r7, const float* __restrict__ r6,
    const float* __restrict__ r5, const float* __restrict__ r4,
    const float* __restrict__ r3, const float* __restrict__ Ag,
    float* __restrict__ e512)
{
    int bx = blockIdx.x, by = blockIdx.y;  // 16x16 grid, 32x32 of e512 each
    int t = threadIdx.x;
    __shared__ float s7[32][33];
    __shared__ float s64[64][65];
    __shared__ float s128[11][12];
    __shared__ float s256[18][19];
    float Ac[3][3], inv;
    load_A(Ag, Ac, inv);
    for (int i = t; i < 1024; i += 256) s7[i >> 5][i & 31] = r7[i] * inv;
    __syncthreads();
    for (int i = t; i < 4096; i += 256) {
        int y = i >> 6, x = i & 63;
        float ctr = s7[y >> 1][x >> 1];
        float sm = 0.f;
#pragma unroll
        for (int dy = -1; dy <= 1; ++dy)
#pragma unroll
            for (int dx = -1; dx <= 1; ++dx) {
                if (dy == 0 && dx == 0) continue;
                int yy = y + dy, xx = x + dx;
                float pe = 0.f;
                if (yy >= 0 && yy < 64 && xx >= 0 && xx < 64) pe = s7[yy >> 1][xx >> 1];
                sm += Ac[dy + 1][dx + 1] * pe;
            }
        s64[y][x] = ctr - sm * inv + r6[i] * inv;
    }
    __syncthreads();
    int R1 = 8 * by - 2, C1 = 8 * bx - 2;
    if (t < 121) {
        int pr = t / 11, pc = t % 11;
        int gy = R1 + pr, gx = C1 + pc;
        if (gy >= 0 && gy < 128 && gx >= 0 && gx < 128) {
            float ctr = s64[gy >> 1][gx >> 1];
            float sm = 0.f;
#pragma unroll
            for (int dy = -1; dy <= 1; ++dy)
#pragma unroll
                for (int dx = -1; dx <= 1; ++dx) {
                    if (dy == 0 && dx == 0) continue;
                    int yy = gy + dy, xx = gx + dx;
                    float pe = 0.f;
                    if (yy >= 0 && yy < 128 && xx >= 0 && xx < 128) pe = s64[yy >> 1][xx >> 1];
                    sm += Ac[dy + 1][dx + 1] * pe;
                }
            s128[pr][pc] = ctr - sm * inv + r5[(size_t)gy * 128 + gx] * inv;
        }
    }
    __syncthreads();
    int R2l = 16 * by - 1, C2l = 16 * bx - 1;
    for (int i = t; i < 324; i += 256) {
        int pr = i / 18, pc = i % 18;
        int gy = R2l + pr, gx = C2l + pc;
        if (gy >= 0 && gy < 256 && gx >= 0 && gx < 256) {
            float ctr = s128[(gy >> 1) - R1][(gx >> 1) - C1];
            float sm = 0.f;
#pragma unroll
            for (int dy = -1; dy <= 1; ++dy)
#pragma unroll
                for (int dx = -1; dx <= 1; ++dx) {
                    if (dy == 0 && dx == 0) continue;
                    int yy = gy + dy, xx = gx + dx;
                    float pe = 0.f;
                    if (yy >= 0 && yy < 256 && xx >= 0 && xx < 256)
                        pe = s128[(yy >> 1) - R1][(xx >> 1) - C1];
                    sm += Ac[dy + 1][dx + 1] * pe;
                }
            s256[pr][pc] = ctr - sm * inv + r4[(size_t)gy * 256 + gx] * inv;
        }
    }
    __syncthreads();
#pragma unroll
    for (int k = 0; k < 4; ++k) {
        int idx = t + 256 * k;
        int y = 32 * by + (idx >> 5), x = 32 * bx + (idx & 31);
        float ctr = s256[(y >> 1) - R2l][(x >> 1) - C2l];
        float sm = 0.f;
#pragma unroll
        for (int dy = -1; dy <= 1; ++dy)
#pragma unroll
            for (int dx = -1; dx <= 1; ++dx) {
                if (dy == 0 && dx == 0) continue;
                int yy = y + dy, xx = x + dx;
                float pe = 0.f;
                if (yy >= 0 && yy < 512 && xx >= 0 && xx < 512)
                    pe = s256[(yy >> 1) - R2l][(xx >> 1) - C2l];
                sm += Ac[dy + 1][dx + 1] * pe;
            }
        e512[(size_t)y * 512 + x] = ctr - sm * inv + r3[(size_t)y * 512 + x] * inv;
    }
}

// ---- fused: e512 -> e1024 -> e2048 -> u update (+ minmax); u tile 128x32 ----
template <bool WANTMM>
__global__ __launch_bounds__(256) void final_fused_kernel(
    const float* __restrict__ u, const float* __restrict__ e512,
    const float* __restrict__ r2, const float* __restrict__ r1,
    const float* __restrict__ Ag, float* __restrict__ uo,
    float* __restrict__ partials)
{
    const int n = N;
    int bx = blockIdx.x, by = blockIdx.y;  // grid (32,128)
    int t = threadIdx.x;
    __shared__ __align__(16) float su[34][136];
    __shared__ float s512v[6][20];
    __shared__ float s1024[10][36];
    __shared__ float s2048[16][68];
    float Ac[3][3], inv;
    load_A(Ag, Ac, inv);
    stage_u_tile(u, su, 32 * by - 1, 128 * bx - 4, t);
    int S5r = 4 * by - 1, S5c = 16 * bx - 1;
    if (t < 108) {
        int pr = t / 18, pc = t - (t / 18) * 18;
        int gy = S5r + pr, gx = S5c + pc;
        if (gy >= 0 && gy < 512 && gx >= 0 && gx < 512)
            s512v[pr][pc] = e512[(size_t)gy * 512 + gx];
    }
    __syncthreads();
    // e1024 patch 10x34
    int R10 = 8 * by - 1, C10 = 32 * bx - 1;
    for (int i = t; i < 340; i += 256) {
        int pr = i / 34, pc = i - (i / 34) * 34;
        int gy = R10 + pr, gx = C10 + pc;
        if (gy >= 0 && gy < 1024 && gx >= 0 && gx < 1024) {
            float ctr = s512v[(gy >> 1) - S5r][(gx >> 1) - S5c];
            float sm = 0.f;
#pragma unroll
            for (int dy = -1; dy <= 1; ++dy)
#pragma unroll
                for (int dx = -1; dx <= 1; ++dx) {
                    if (dy == 0 && dx == 0) continue;
                    int yy = gy + dy, xx = gx + dx;
                    float pe = 0.f;
                    if (yy >= 0 && yy < 1024 && xx >= 0 && xx < 1024)
                        pe = s512v[(yy >> 1) - S5r][(xx >> 1) - S5c];
                    sm += Ac[dy + 1][dx + 1] * pe;
                }
            s1024[pr][pc] = ctr - sm * inv + r2[(size_t)gy * 1024 + gx] * inv;
        }
    }
    __syncthreads();
    // e2048 tile 16x64
    int E2r = 16 * by, E2c = 64 * bx;
#pragma unroll
    for (int k = 0; k < 4; ++k) {
        int idx = t + 256 * k;
        int pr = idx >> 6, pc = idx & 63;
        int gy = E2r + pr, gx = E2c + pc;
        float ctr = s1024[(gy >> 1) - R10][(gx >> 1) - C10];
        float sm = 0.f;
#pragma unroll
        for (int dy = -1; dy <= 1; ++dy)
#pragma unroll
            for (int dx = -1; dx <= 1; ++dx) {
                if (dy == 0 && dx == 0) continue;
                int yy = gy + dy, xx = gx + dx;
                float pe = 0.f;
                if (yy >= 0 && yy < 2048 && xx >= 0 && xx < 2048)
                    pe = s1024[(yy >> 1) - R10][(xx >> 1) - C10];
                sm += Ac[dy + 1][dx + 1] * pe;
            }
        s2048[pr][pc] = ctr - sm * inv + r1[(size_t)gy * 2048 + gx] * inv;
    }
    __syncthreads();
    // u update, 4 rows of float4 per thread
    int txx = t & 31, tyy = t >> 5;
    float mn = 3.402823466e+38f, mx = -3.402823466e+38f;
#pragma unroll
    for (int rr = 0; rr < 4; ++rr) {
        int yl = tyy + 8 * rr;
        int y = 32 * by + yl;
        float p[3][6];
#pragma unroll
        for (int a = 0; a < 3; ++a) {
            const float* row = su[yl + a];
            float L = row[4 * txx + 3];
            float4 m = *(const float4*)&row[4 * txx + 4];
            float R = row[4 * txx + 8];
            p[a][0] = L; p[a][1] = m.x; p[a][2] = m.y;
            p[a][3] = m.z; p[a][4] = m.w; p[a][5] = R;
        }
        float out[4];
#pragma unroll
        for (int cc = 0; cc < 4; ++cc) {
            float sm = 0.f;
#pragma unroll
            for (int i2 = 0; i2 < 3; ++i2)
#pragma unroll
                for (int j = 0; j < 3; ++j) sm += Ac[i2][j] * p[i2][cc + j];
            float e = s2048[yl >> 1][(4 * txx + cc) >> 1];
            out[cc] = p[1][cc + 1] - e - sm * inv;
        }
        *(float4*)&uo[(size_t)y * n + 128 * bx + 4 * txx] =
            make_float4(out[0], out[1], out[2], out[3]);
        if (WANTMM) {
            mn = fminf(mn, fminf(fminf(out[0], out[1]), fminf(out[2], out[3])));
            mx = fmaxf(mx, fmaxf(fmaxf(out[0], out[1]), fmaxf(out[2], out[3])));
        }
    }
    if (WANTMM) {
#pragma unroll
        for (int off = 32; off > 0; off >>= 1) {
            mn = fminf(mn, __shfl_down(mn, off));
            mx = fmaxf(mx, __shfl_down(mx, off));
        }
        __shared__ float smn[4], smx[4];
        int lane = t & 63, wv = t >> 6;
        if (lane == 0) { smn[wv] = mn; smx[wv] = mx; }
        __syncthreads();
        if (t == 0) {
            mn = smn[0]; mx = smx[0];
            for (int wq = 1; wq < 4; ++wq) { mn = fminf(mn, smn[wq]); mx = fmaxf(mx, smx[wq]); }
            int bid = by * 32 + bx;
            partials[2 * bid] = mn;
            partials[2 * bid + 1] = mx;
        }
    }
}

__global__ __launch_bounds__(1024) void minmax_final_kernel(
    const float* __restrict__ partials, float* __restrict__ mm)
{
    float mn = 3.402823466e+38f, mx = -3.402823466e+38f;
    for (int i = threadIdx.x; i < 4096; i += 1024) {
        mn = fminf(mn, partials[2 * i]);
        mx = fmaxf(mx, partials[2 * i + 1]);
    }
#pragma unroll
    for (int off = 32; off > 0; off >>= 1) {
        mn = fminf(mn, __shfl_down(mn, off));
        mx = fmaxf(mx, __shfl_down(mx, off));
    }
    __shared__ float smn[16], smx[16];
    int lane = threadIdx.x & 63, wv = threadIdx.x >> 6;
    if (lane == 0) { smn[wv] = mn; smx[wv] = mx; }
    __syncthreads();
    if (threadIdx.x == 0) {
        mn = smn[0]; mx = smx[0];
        for (int w = 1; w < 16; ++w) { mn = fminf(mn, smn[w]); mx = fmaxf(mx, smx[w]); }
        mm[0] = mn;
        mm[1] = mx;
    }
}

__global__ __launch_bounds__(256) void normalize_kernel(
    float* __restrict__ u, const float* __restrict__ mm)
{
    size_t i = ((size_t)blockIdx.x * 256 + threadIdx.x) * 4;
    float mn = mm[0];
    float sc = 1.0f / (mm[1] - mm[0]);
    float4 v = *(float4*)&u[i];
    v.x = (v.x - mn) * sc;
    v.y = (v.y - mn) * sc;
    v.z = (v.z - mn) * sc;
    v.w = (v.w - mn) * sc;
    *(float4*)&u[i] = v;
}

extern "C" void kernel_launch(void* const* d_in, const int* in_sizes, int n_in,
                              void* d_out, int out_size, void* d_ws, size_t ws_size,
                              hipStream_t stream)
{
    const float* A  = (const float*)d_in[0];
    const float* u0 = (const float*)d_in[1];
    float* uout = (float*)d_out;
    float* ws = (float*)d_ws;

    size_t off = 0;
    float* r1 = ws + off; off += 2048ull * 2048;
    float* r2 = ws + off; off += 1024ull * 1024;
    float* r3 = ws + off; off += 512ull * 512;
    float* r4 = ws + off; off += 256ull * 256;
    float* r5 = ws + off; off += 128ull * 128;
    float* r6 = ws + off; off += 64ull * 64;
    float* r7 = ws + off; off += 32ull * 32;
    float* e5 = ws + off; off += 512ull * 512;
    float* uA = ws + off; off += 4096ull * 4096;
    float* partials = ws + off; off += 8192;
    float* mm = ws + off; off += 2;

    dim3 blk(256);
    for (int it = 0; it < 4; ++it) {
        const float* us = (it == 0) ? u0 : ((it == 2) ? uout : uA);
        float* dst = (it & 1) ? uout : uA;
        smooth_restrict_kernel<<<dim3(32, 128), blk, 0, stream>>>(us, A, r1);
        multirestrict_kernel<<<dim3(32, 32), blk, 0, stream>>>(r1, r2, r3, r4, r5, r6, r7);
        coarse_up_kernel<<<dim3(16, 16), blk, 0, stream>>>(r7, r6, r5, r4, r3, A, e5);
        if (it == 3)
            final_fused_kernel<true><<<dim3(32, 128), blk, 0, stream>>>(us, e5, r2, r1, A, dst, partials);
        else
            final_fused_kernel<false><<<dim3(32, 128), blk, 0, stream>>>(us, e5, r2, r1, A, dst, partials);
    }
    minmax_final_kernel<<<1, 1024, 0, stream>>>(partials, mm);
    normalize_kernel<<<16384, 256, 0, stream>>>(uout, mm);
}

// Round 6
// 340.579 us; speedup vs baseline: 1.2416x; 1.2416x over previous
//
#include <hip/hip_runtime.h>

#define N 4096

__device__ __forceinline__ void load_A(const float* __restrict__ Ag,
                                       float Ac[3][3], float& inv)
{
#pragma unroll
    for (int i = 0; i < 9; ++i) Ac[i / 3][i % 3] = Ag[i];
    inv = 1.0f / Ac[1][1];
    Ac[1][1] = 0.f;
}

// Boundary value of u_bc at (gy,gx): replicate edges, zero the frame corners.
__device__ __forceinline__ float edge_val(const float* __restrict__ u,
                                          int gy, int gx)
{
    const int n = N;
    bool oy = (gy < 0) | (gy >= n);
    bool ox = (gx < 0) | (gx >= n);
    if (oy & ox) return 0.f;
    int cy = min(max(gy, 0), n - 1), cx = min(max(gx, 0), n - 1);
    return u[(size_t)cy * n + cx];
}

struct Row { float4 m; float L, R; };

// Load one u row segment: lane holds cols x0+4*lane .. +3, plus L/R neighbors.
__device__ __forceinline__ Row load_row(const float* __restrict__ u,
                                        int gy, int x0, int lane)
{
    const int n = N;
    Row r;
    int cy = min(max(gy, 0), n - 1);
    r.m = *(const float4*)&u[(size_t)cy * n + x0 + 4 * lane];
    r.L = __shfl_up(r.m.w, 1);
    r.R = __shfl_down(r.m.x, 1);
    if (lane == 0)  r.L = edge_val(u, gy, x0 - 1);
    if (lane == 63) r.R = edge_val(u, gy, x0 + 256);
    return r;
}

// ---- fused smooth(bc(u)) + 2x2 restrict -> r1 (2048^2), register-only ----
// Block: 256 thr = 4 waves; wave handles 4 r1 rows x 128 r1 cols. Grid (16,128).
__global__ __launch_bounds__(256) void smooth_restrict_kernel(
    const float* __restrict__ u, const float* __restrict__ Ag,
    float* __restrict__ r1)
{
    int t = threadIdx.x, lane = t & 63, w = t >> 6;
    int bx = blockIdx.x, by = blockIdx.y;
    int x0 = 256 * bx;
    int Y0 = 16 * by + 4 * w;
    float Ac[3][3], inv;
    load_A(Ag, Ac, inv);
    float wt[4][4];
#pragma unroll
    for (int a = 0; a < 4; ++a)
#pragma unroll
        for (int b = 0; b < 4; ++b) wt[a][b] = 0.f;
#pragma unroll
    for (int r = 0; r < 2; ++r)
#pragma unroll
        for (int c = 0; c < 2; ++c)
#pragma unroll
            for (int i = 0; i < 3; ++i)
#pragma unroll
                for (int j = 0; j < 3; ++j) wt[r + i][c + j] += Ac[i][j];

#pragma unroll
    for (int q = 0; q < 4; ++q) {
        int Y = Y0 + q;
        float o0 = 0.f, o1 = 0.f;
#pragma unroll
        for (int a = 0; a < 4; ++a) {
            Row rw = load_row(u, 2 * Y - 1 + a, x0, lane);
            float v[6] = {rw.L, rw.m.x, rw.m.y, rw.m.z, rw.m.w, rw.R};
#pragma unroll
            for (int b = 0; b < 4; ++b) {
                o0 += wt[a][b] * v[b];
                o1 += wt[a][b] * v[b + 2];
            }
        }
        *(float2*)&r1[(size_t)Y * 2048 + 128 * bx + 2 * lane] =
            make_float2(0.25f * o0, 0.25f * o1);
    }
}

// ---- one-shot restriction tree: r1 -> r2..r7 ----
__global__ __launch_bounds__(256) void multirestrict_kernel(
    const float* __restrict__ r1, float* __restrict__ r2, float* __restrict__ r3,
    float* __restrict__ r4, float* __restrict__ r5, float* __restrict__ r6,
    float* __restrict__ r7)
{
    const int n1 = 2048, n2 = 1024, n3 = 512, n4 = 256, n5 = 128, n6 = 64, n7 = 32;
    int BX = blockIdx.x, BY = blockIdx.y;
    __shared__ __align__(16) float s2[32][36];
    __shared__ float s3[16][17];
    __shared__ float s4[8][9];
    __shared__ float s5[4][5];
    __shared__ float s6[2][3];
    int t = threadIdx.x;
    {
        int R = t >> 3, c8 = (t & 7) * 8;
        const float* base0 = &r1[(size_t)(BY * 64 + 2 * R) * n1 + BX * 64 + c8];
        const float* base1 = base0 + n1;
        float4 a0 = ((const float4*)base0)[0], a1 = ((const float4*)base0)[1];
        float4 b0 = ((const float4*)base1)[0], b1 = ((const float4*)base1)[1];
        float4 o;
        o.x = 0.25f * (a0.x + a0.y + b0.x + b0.y);
        o.y = 0.25f * (a0.z + a0.w + b0.z + b0.w);
        o.z = 0.25f * (a1.x + a1.y + b1.x + b1.y);
        o.w = 0.25f * (a1.z + a1.w + b1.z + b1.w);
        *(float4*)&r2[(size_t)(BY * 32 + R) * n2 + BX * 32 + (t & 7) * 4] = o;
        *(float4*)&s2[R][(t & 7) * 4] = o;
    }
    __syncthreads();
    {
        int y = t >> 4, x = t & 15;
        float v = 0.25f * (s2[2 * y][2 * x] + s2[2 * y][2 * x + 1] +
                           s2[2 * y + 1][2 * x] + s2[2 * y + 1][2 * x + 1]);
        r3[(size_t)(BY * 16 + y) * n3 + BX * 16 + x] = v;
        s3[y][x] = v;
    }
    __syncthreads();
    if (t < 64) {
        int y = t >> 3, x = t & 7;
        float v = 0.25f * (s3[2 * y][2 * x] + s3[2 * y][2 * x + 1] +
                           s3[2 * y + 1][2 * x] + s3[2 * y + 1][2 * x + 1]);
        r4[(size_t)(BY * 8 + y) * n4 + BX * 8 + x] = v;
        s4[y][x] = v;
    }
    __syncthreads();
    if (t < 16) {
        int y = t >> 2, x = t & 3;
        float v = 0.25f * (s4[2 * y][2 * x] + s4[2 * y][2 * x + 1] +
                           s4[2 * y + 1][2 * x] + s4[2 * y + 1][2 * x + 1]);
        r5[(size_t)(BY * 4 + y) * n5 + BX * 4 + x] = v;
        s5[y][x] = v;
    }
    __syncthreads();
    if (t < 4) {
        int y = t >> 1, x = t & 1;
        float v = 0.25f * (s5[2 * y][2 * x] + s5[2 * y][2 * x + 1] +
                           s5[2 * y + 1][2 * x] + s5[2 * y + 1][2 * x + 1]);
        r6[(size_t)(BY * 2 + y) * n6 + BX * 2 + x] = v;
        s6[y][x] = v;
    }
    __syncthreads();
    if (t == 0) {
        r7[(size_t)BY * n7 + BX] =
            0.25f * (s6[0][0] + s6[0][1] + s6[1][0] + s6[1][1]);
    }
}

// ---- fused coarse up-chain: r7..r3 -> e@512 ----
__global__ __launch_bounds__(256) void coarse_up_kernel(
    const float* __restrict__ r7, const float* __restrict__ r6,
    const float* __restrict__ r5, const float* __restrict__ r4,
    const float* __restrict__ r3, const float* __restrict__ Ag,
    float* __restrict__ e512)
{
    int bx = blockIdx.x, by = blockIdx.y;  // 16x16 grid, 32x32 of e512 each
    int t = threadIdx.x;
    __shared__ float s7[32][33];
    __shared__ float s64[64][65];
    __shared__ float s128[11][12];
    __shared__ float s256[18][19];
    float Ac[3][3], inv;
    load_A(Ag, Ac, inv);
    for (int i = t; i < 1024; i += 256) s7[i >> 5][i & 31] = r7[i] * inv;
    __syncthreads();
    for (int i = t; i < 4096; i += 256) {
        int y = i >> 6, x = i & 63;
        float ctr = s7[y >> 1][x >> 1];
        float sm = 0.f;
#pragma unroll
        for (int dy = -1; dy <= 1; ++dy)
#pragma unroll
            for (int dx = -1; dx <= 1; ++dx) {
                if (dy == 0 && dx == 0) continue;
                int yy = y + dy, xx = x + dx;
                float pe = 0.f;
                if (yy >= 0 && yy < 64 && xx >= 0 && xx < 64) pe = s7[yy >> 1][xx >> 1];
                sm += Ac[dy + 1][dx + 1] * pe;
            }
        s64[y][x] = ctr - sm * inv + r6[i] * inv;
    }
    __syncthreads();
    int R1 = 8 * by - 2, C1 = 8 * bx - 2;
    if (t < 121) {
        int pr = t / 11, pc = t % 11;
        int gy = R1 + pr, gx = C1 + pc;
        if (gy >= 0 && gy < 128 && gx >= 0 && gx < 128) {
            float ctr = s64[gy >> 1][gx >> 1];
            float sm = 0.f;
#pragma unroll
            for (int dy = -1; dy <= 1; ++dy)
#pragma unroll
                for (int dx = -1; dx <= 1; ++dx) {
                    if (dy == 0 && dx == 0) continue;
                    int yy = gy + dy, xx = gx + dx;
                    float pe = 0.f;
                    if (yy >= 0 && yy < 128 && xx >= 0 && xx < 128) pe = s64[yy >> 1][xx >> 1];
                    sm += Ac[dy + 1][dx + 1] * pe;
                }
            s128[pr][pc] = ctr - sm * inv + r5[(size_t)gy * 128 + gx] * inv;
        }
    }
    __syncthreads();
    int R2l = 16 * by - 1, C2l = 16 * bx - 1;
    for (int i = t; i < 324; i += 256) {
        int pr = i / 18, pc = i % 18;
        int gy = R2l + pr, gx = C2l + pc;
        if (gy >= 0 && gy < 256 && gx >= 0 && gx < 256) {
            float ctr = s128[(gy >> 1) - R1][(gx >> 1) - C1];
            float sm = 0.f;
#pragma unroll
            for (int dy = -1; dy <= 1; ++dy)
#pragma unroll
                for (int dx = -1; dx <= 1; ++dx) {
                    if (dy == 0 && dx == 0) continue;
                    int yy = gy + dy, xx = gx + dx;
                    float pe = 0.f;
                    if (yy >= 0 && yy < 256 && xx >= 0 && xx < 256)
                        pe = s128[(yy >> 1) - R1][(xx >> 1) - C1];
                    sm += Ac[dy + 1][dx + 1] * pe;
                }
            s256[pr][pc] = ctr - sm * inv + r4[(size_t)gy * 256 + gx] * inv;
        }
    }
    __syncthreads();
#pragma unroll
    for (int k = 0; k < 4; ++k) {
        int idx = t + 256 * k;
        int y = 32 * by + (idx >> 5), x = 32 * bx + (idx & 31);
        float ctr = s256[(y >> 1) - R2l][(x >> 1) - C2l];
        float sm = 0.f;
#pragma unroll
        for (int dy = -1; dy <= 1; ++dy)
#pragma unroll
            for (int dx = -1; dx <= 1; ++dx) {
                if (dy == 0 && dx == 0) continue;
                int yy = y + dy, xx = x + dx;
                float pe = 0.f;
                if (yy >= 0 && yy < 512 && xx >= 0 && xx < 512)
                    pe = s256[(yy >> 1) - R2l][(xx >> 1) - C2l];
                sm += Ac[dy + 1][dx + 1] * pe;
            }
        e512[(size_t)y * 512 + x] = ctr - sm * inv + r3[(size_t)y * 512 + x] * inv;
    }
}

// ---- fused: e512 -> e1024 (LDS) -> e2048 (regs) -> u update, no u-LDS ----
// Block: 256 thr = 4 waves; u tile 256 cols x 32 rows. Grid (16,128).
template <bool WANTMM>
__global__ __launch_bounds__(256) void final_fused_kernel(
    const float* __restrict__ u, const float* __restrict__ e512,
    const float* __restrict__ r2, const float* __restrict__ r1,
    const float* __restrict__ Ag, float* __restrict__ uo,
    float* __restrict__ partials)
{
    const int n = N;
    int t = threadIdx.x, lane = t & 63, w = t >> 6;
    int bx = blockIdx.x, by = blockIdx.y;
    int x0 = 256 * bx, y0 = 32 * by;
    __shared__ float s512v[6][36];   // e512 rows 4by-1.. (6), cols 32bx-1.. (34 used)
    __shared__ float s1024[10][68];  // e1024 rows 8by-1.. (10), cols 64bx-1.. (66 used)
    float Ac[3][3], inv;
    load_A(Ag, Ac, inv);
    int S5r = 4 * by - 1, S5c = 32 * bx - 1;
    if (t < 216) {
        int pr = t / 36, pc = t - (t / 36) * 36;
        int gy = S5r + pr, gx = S5c + pc;
        float v = 0.f;
        if (pc < 34 && gy >= 0 && gy < 512 && gx >= 0 && gx < 512)
            v = e512[(size_t)gy * 512 + gx];
        s512v[pr][pc] = v;  // oob entries = 0 (zero-padding of e)
    }
    __syncthreads();
    // e1024 patch 10x66 (oob entries = 0)
    int R10 = 8 * by - 1, C10 = 64 * bx - 1;
    for (int i = t; i < 680; i += 256) {
        int pr = i / 68, pc = i - (i / 68) * 68;
        if (pc < 66) {
            int gy = R10 + pr, gx = C10 + pc;
            float val = 0.f;
            if (gy >= 0 && gy < 1024 && gx >= 0 && gx < 1024) {
                float ctr = s512v[(gy >> 1) - S5r][(gx >> 1) - S5c];
                float sm = 0.f;
#pragma unroll
                for (int dy = -1; dy <= 1; ++dy)
#pragma unroll
                    for (int dx = -1; dx <= 1; ++dx) {
                        if (dy == 0 && dx == 0) continue;
                        // oob maps into zero-filled halo cells of s512v
                        sm += Ac[dy + 1][dx + 1] *
                              s512v[((gy + dy) >> 1) - S5r][((gx + dx) >> 1) - S5c];
                    }
                val = ctr - sm * inv + r2[(size_t)gy * 1024 + gx] * inv;
            }
            s1024[pr][pc] = val;
        }
    }
    __syncthreads();
    // per-thread e2048: 4 rows x 2 cols (exact r1 footprint, coalesced float2)
    float e2[4][2];
    int EY0 = 16 * by + 4 * w, EX0 = 128 * bx + 2 * lane;
#pragma unroll
    for (int a = 0; a < 4; ++a) {
        int gy = EY0 + a;
        float2 rv = *(const float2*)&r1[(size_t)gy * 2048 + EX0];
#pragma unroll
        for (int b = 0; b < 2; ++b) {
            int gx = EX0 + b;
            float ctr = s1024[(gy >> 1) - R10][(gx >> 1) - C10];
            float sm = 0.f;
#pragma unroll
            for (int dy = -1; dy <= 1; ++dy)
#pragma unroll
                for (int dx = -1; dx <= 1; ++dx) {
                    if (dy == 0 && dx == 0) continue;
                    sm += Ac[dy + 1][dx + 1] *
                          s1024[((gy + dy) >> 1) - R10][((gx + dx) >> 1) - C10];
                }
            float rj = (b == 0) ? rv.x : rv.y;
            e2[a][b] = ctr - sm * inv + rj * inv;
        }
    }
    // u update: 8 rows, rolling 3-row register window
    float mn = 3.402823466e+38f, mx = -3.402823466e+38f;
    int yb = y0 + 8 * w;
    Row ra = load_row(u, yb - 1, x0, lane);
    Row rb = load_row(u, yb, x0, lane);
#pragma unroll
    for (int r = 0; r < 8; ++r) {
        int y = yb + r;
        Row rc = load_row(u, y + 1, x0, lane);
        float va[6] = {ra.L, ra.m.x, ra.m.y, ra.m.z, ra.m.w, ra.R};
        float vb[6] = {rb.L, rb.m.x, rb.m.y, rb.m.z, rb.m.w, rb.R};
        float vc[6] = {rc.L, rc.m.x, rc.m.y, rc.m.z, rc.m.w, rc.R};
        float out[4];
#pragma unroll
        for (int c = 0; c < 4; ++c) {
            float sm = Ac[0][0] * va[c] + Ac[0][1] * va[c + 1] + Ac[0][2] * va[c + 2]
                     + Ac[1][0] * vb[c]                        + Ac[1][2] * vb[c + 2]
                     + Ac[2][0] * vc[c] + Ac[2][1] * vc[c + 1] + Ac[2][2] * vc[c + 2];
            out[c] = vb[c + 1] - e2[r >> 1][c >> 1] - sm * inv;
        }
        *(float4*)&uo[(size_t)y * n + x0 + 4 * lane] =
            make_float4(out[0], out[1], out[2], out[3]);
        if (WANTMM) {
            mn = fminf(mn, fminf(fminf(out[0], out[1]), fminf(out[2], out[3])));
            mx = fmaxf(mx, fmaxf(fmaxf(out[0], out[1]), fmaxf(out[2], out[3])));
        }
        ra = rb;
        rb = rc;
    }
    if (WANTMM) {
#pragma unroll
        for (int off = 32; off > 0; off >>= 1) {
            mn = fminf(mn, __shfl_down(mn, off));
            mx = fmaxf(mx, __shfl_down(mx, off));
        }
        __shared__ float smn[4], smx[4];
        if (lane == 0) { smn[w] = mn; smx[w] = mx; }
        __syncthreads();
        if (t == 0) {
            mn = smn[0]; mx = smx[0];
            for (int wq = 1; wq < 4; ++wq) { mn = fminf(mn, smn[wq]); mx = fmaxf(mx, smx[wq]); }
            int bid = by * 16 + bx;
            partials[2 * bid] = mn;
            partials[2 * bid + 1] = mx;
        }
    }
}

__global__ __launch_bounds__(1024) void minmax_final_kernel(
    const float* __restrict__ partials, float* __restrict__ mm)
{
    float mn = 3.402823466e+38f, mx = -3.402823466e+38f;
    for (int i = threadIdx.x; i < 2048; i += 1024) {
        mn = fminf(mn, partials[2 * i]);
        mx = fmaxf(mx, partials[2 * i + 1]);
    }
#pragma unroll
    for (int off = 32; off > 0; off >>= 1) {
        mn = fminf(mn, __shfl_down(mn, off));
        mx = fmaxf(mx, __shfl_down(mx, off));
    }
    __shared__ float smn[16], smx[16];
    int lane = threadIdx.x & 63, wv = threadIdx.x >> 6;
    if (lane == 0) { smn[wv] = mn; smx[wv] = mx; }
    __syncthreads();
    if (threadIdx.x == 0) {
        mn = smn[0]; mx = smx[0];
        for (int w = 1; w < 16; ++w) { mn = fminf(mn, smn[w]); mx = fmaxf(mx, smx[w]); }
        mm[0] = mn;
        mm[1] = mx;
    }
}

__global__ __launch_bounds__(256) void normalize_kernel(
    float* __restrict__ u, const float* __restrict__ mm)
{
    size_t i = ((size_t)blockIdx.x * 256 + threadIdx.x) * 4;
    float mn = mm[0];
    float sc = 1.0f / (mm[1] - mm[0]);
    float4 v = *(float4*)&u[i];
    v.x = (v.x - mn) * sc;
    v.y = (v.y - mn) * sc;
    v.z = (v.z - mn) * sc;
    v.w = (v.w - mn) * sc;
    *(float4*)&u[i] = v;
}

extern "C" void kernel_launch(void* const* d_in, const int* in_sizes, int n_in,
                              void* d_out, int out_size, void* d_ws, size_t ws_size,
                              hipStream_t stream)
{
    const float* A  = (const float*)d_in[0];
    const float* u0 = (const float*)d_in[1];
    float* uout = (float*)d_out;
    float* ws = (float*)d_ws;

    size_t off = 0;
    float* r1 = ws + off; off += 2048ull * 2048;
    float* r2 = ws + off; off += 1024ull * 1024;
    float* r3 = ws + off; off += 512ull * 512;
    float* r4 = ws + off; off += 256ull * 256;
    float* r5 = ws + off; off += 128ull * 128;
    float* r6 = ws + off; off += 64ull * 64;
    float* r7 = ws + off; off += 32ull * 32;
    float* e5 = ws + off; off += 512ull * 512;
    float* uA = ws + off; off += 4096ull * 4096;
    float* partials = ws + off; off += 4096;
    float* mm = ws + off; off += 2;

    dim3 blk(256);
    for (int it = 0; it < 4; ++it) {
        const float* us = (it == 0) ? u0 : ((it == 2) ? uout : uA);
        float* dst = (it & 1) ? uout : uA;
        smooth_restrict_kernel<<<dim3(16, 128), blk, 0, stream>>>(us, A, r1);
        multirestrict_kernel<<<dim3(32, 32), blk, 0, stream>>>(r1, r2, r3, r4, r5, r6, r7);
        coarse_up_kernel<<<dim3(16, 16), blk, 0, stream>>>(r7, r6, r5, r4, r3, A, e5);
        if (it == 3)
            final_fused_kernel<true><<<dim3(16, 128), blk, 0, stream>>>(us, e5, r2, r1, A, dst, partials);
        else
            final_fused_kernel<false><<<dim3(16, 128), blk, 0, stream>>>(us, e5, r2, r1, A, dst, partials);
    }
    minmax_final_kernel<<<1, 1024, 0, stream>>>(partials, mm);
    normalize_kernel<<<16384, 256, 0, stream>>>(uout, mm);
}

// Round 7
// 291.698 us; speedup vs baseline: 1.4496x; 1.1676x over previous
//
#include <hip/hip_runtime.h>

#define N 4096

__device__ __forceinline__ void load_A(const float* __restrict__ Ag,
                                       float Ac[3][3], float& inv)
{
#pragma unroll
    for (int i = 0; i < 9; ++i) Ac[i / 3][i % 3] = Ag[i];
    inv = 1.0f / Ac[1][1];
    Ac[1][1] = 0.f;
}

// Branch-free u_bc row segment: lane covers cols xm..xm+3 (aligned float4),
// plus L (xm-1) and R (xm+4) via clamped scalar loads. Corner-zeroing only
// applies in y-edge waves (wave-uniform 'yedge').
__device__ __forceinline__ void load_row6(const float* __restrict__ u,
                                          int gy, int xm, int colL, int colR,
                                          bool cornL, bool cornR, bool yedge,
                                          float v[6])
{
    int cy = min(max(gy, 0), N - 1);
    const float* rowp = &u[(size_t)cy * N];
    float4 m = *(const float4*)&rowp[xm];
    float L = rowp[colL];
    float R = rowp[colR];
    if (yedge) {
        bool oob = (gy < 0) | (gy >= N);
        if (oob & cornL) L = 0.f;
        if (oob & cornR) R = 0.f;
    }
    v[0] = L; v[1] = m.x; v[2] = m.y; v[3] = m.z; v[4] = m.w; v[5] = R;
}

// ---- fused smooth(bc(u)) + 2x2 restrict -> r1 (2048^2), register-only ----
// Wave: 4 r1 rows x 128 r1 cols; preloads all 10 u rows for max MLP. Grid (16,128).
__global__ __launch_bounds__(256) void smooth_restrict_kernel(
    const float* __restrict__ u, const float* __restrict__ Ag,
    float* __restrict__ r1)
{
    int t = threadIdx.x, lane = t & 63, w = t >> 6;
    int bx = blockIdx.x, by = blockIdx.y;
    int x0 = 256 * bx;
    int Y0 = 16 * by + 4 * w;
    int gy0 = 2 * Y0 - 1;
    bool yedge = (gy0 < 0) | (gy0 + 9 >= N);
    float Ac[3][3], inv;
    load_A(Ag, Ac, inv);
    float wt[4][4];
#pragma unroll
    for (int a = 0; a < 4; ++a)
#pragma unroll
        for (int b = 0; b < 4; ++b) wt[a][b] = 0.f;
#pragma unroll
    for (int r = 0; r < 2; ++r)
#pragma unroll
        for (int c = 0; c < 2; ++c)
#pragma unroll
            for (int i = 0; i < 3; ++i)
#pragma unroll
                for (int j = 0; j < 3; ++j) wt[r + i][c + j] += Ac[i][j];

    int xm = x0 + 4 * lane;
    int colL = max(xm - 1, 0), colR = min(xm + 4, N - 1);
    bool cornL = (xm - 1 < 0), cornR = (xm + 4 >= N);
    float v[10][6];
#pragma unroll
    for (int rr = 0; rr < 10; ++rr)
        load_row6(u, gy0 + rr, xm, colL, colR, cornL, cornR, yedge, v[rr]);

#pragma unroll
    for (int q = 0; q < 4; ++q) {
        float o0 = 0.f, o1 = 0.f;
#pragma unroll
        for (int a = 0; a < 4; ++a) {
            const float* vv = v[2 * q + a];
#pragma unroll
            for (int b = 0; b < 4; ++b) {
                o0 += wt[a][b] * vv[b];
                o1 += wt[a][b] * vv[b + 2];
            }
        }
        *(float2*)&r1[(size_t)(Y0 + q) * 2048 + 128 * bx + 2 * lane] =
            make_float2(0.25f * o0, 0.25f * o1);
    }
}

// ---- one-shot restriction tree: r1 -> r2..r7 ----
__global__ __launch_bounds__(256) void multirestrict_kernel(
    const float* __restrict__ r1, float* __restrict__ r2, float* __restrict__ r3,
    float* __restrict__ r4, float* __restrict__ r5, float* __restrict__ r6,
    float* __restrict__ r7)
{
    const int n1 = 2048, n2 = 1024, n3 = 512, n4 = 256, n5 = 128, n6 = 64, n7 = 32;
    int BX = blockIdx.x, BY = blockIdx.y;
    __shared__ __align__(16) float s2[32][36];
    __shared__ float s3[16][17];
    __shared__ float s4[8][9];
    __shared__ float s5[4][5];
    __shared__ float s6[2][3];
    int t = threadIdx.x;
    {
        int R = t >> 3, c8 = (t & 7) * 8;
        const float* base0 = &r1[(size_t)(BY * 64 + 2 * R) * n1 + BX * 64 + c8];
        const float* base1 = base0 + n1;
        float4 a0 = ((const float4*)base0)[0], a1 = ((const float4*)base0)[1];
        float4 b0 = ((const float4*)base1)[0], b1 = ((const float4*)base1)[1];
        float4 o;
        o.x = 0.25f * (a0.x + a0.y + b0.x + b0.y);
        o.y = 0.25f * (a0.z + a0.w + b0.z + b0.w);
        o.z = 0.25f * (a1.x + a1.y + b1.x + b1.y);
        o.w = 0.25f * (a1.z + a1.w + b1.z + b1.w);
        *(float4*)&r2[(size_t)(BY * 32 + R) * n2 + BX * 32 + (t & 7) * 4] = o;
        *(float4*)&s2[R][(t & 7) * 4] = o;
    }
    __syncthreads();
    {
        int y = t >> 4, x = t & 15;
        float v = 0.25f * (s2[2 * y][2 * x] + s2[2 * y][2 * x + 1] +
                           s2[2 * y + 1][2 * x] + s2[2 * y + 1][2 * x + 1]);
        r3[(size_t)(BY * 16 + y) * n3 + BX * 16 + x] = v;
        s3[y][x] = v;
    }
    __syncthreads();
    if (t < 64) {
        int y = t >> 3, x = t & 7;
        float v = 0.25f * (s3[2 * y][2 * x] + s3[2 * y][2 * x + 1] +
                           s3[2 * y + 1][2 * x] + s3[2 * y + 1][2 * x + 1]);
        r4[(size_t)(BY * 8 + y) * n4 + BX * 8 + x] = v;
        s4[y][x] = v;
    }
    __syncthreads();
    if (t < 16) {
        int y = t >> 2, x = t & 3;
        float v = 0.25f * (s4[2 * y][2 * x] + s4[2 * y][2 * x + 1] +
                           s4[2 * y + 1][2 * x] + s4[2 * y + 1][2 * x + 1]);
        r5[(size_t)(BY * 4 + y) * n5 + BX * 4 + x] = v;
        s5[y][x] = v;
    }
    __syncthreads();
    if (t < 4) {
        int y = t >> 1, x = t & 1;
        float v = 0.25f * (s5[2 * y][2 * x] + s5[2 * y][2 * x + 1] +
                           s5[2 * y + 1][2 * x] + s5[2 * y + 1][2 * x + 1]);
        r6[(size_t)(BY * 2 + y) * n6 + BX * 2 + x] = v;
        s6[y][x] = v;
    }
    __syncthreads();
    if (t == 0) {
        r7[(size_t)BY * n7 + BX] =
            0.25f * (s6[0][0] + s6[0][1] + s6[1][0] + s6[1][1]);
    }
}

// ---- fused coarse up-chain: r7..r3 -> e@512 ----
__global__ __launch_bounds__(256) void coarse_up_kernel(
    const float* __restrict__ r7, const float* __restrict__ r6,
    const float* __restrict__ r5, const float* __restrict__ r4,
    const float* __restrict__ r3, const float* __restrict__ Ag,
    float* __restrict__ e512)
{
    int bx = blockIdx.x, by = blockIdx.y;  // 16x16 grid, 32x32 of e512 each
    int t = threadIdx.x;
    __shared__ float s7[32][33];
    __shared__ float s64[64][65];
    __shared__ float s128[11][12];
    __shared__ float s256[18][19];
    float Ac[3][3], inv;
    load_A(Ag, Ac, inv);
    for (int i = t; i < 1024; i += 256) s7[i >> 5][i & 31] = r7[i] * inv;
    __syncthreads();
    for (int i = t; i < 4096; i += 256) {
        int y = i >> 6, x = i & 63;
        float ctr = s7[y >> 1][x >> 1];
        float sm = 0.f;
#pragma unroll
        for (int dy = -1; dy <= 1; ++dy)
#pragma unroll
            for (int dx = -1; dx <= 1; ++dx) {
                if (dy == 0 && dx == 0) continue;
                int yy = y + dy, xx = x + dx;
                float pe = 0.f;
                if (yy >= 0 && yy < 64 && xx >= 0 && xx < 64) pe = s7[yy >> 1][xx >> 1];
                sm += Ac[dy + 1][dx + 1] * pe;
            }
        s64[y][x] = ctr - sm * inv + r6[i] * inv;
    }
    __syncthreads();
    int R1 = 8 * by - 2, C1 = 8 * bx - 2;
    if (t < 121) {
        int pr = t / 11, pc = t % 11;
        int gy = R1 + pr, gx = C1 + pc;
        if (gy >= 0 && gy < 128 && gx >= 0 && gx < 128) {
            float ctr = s64[gy >> 1][gx >> 1];
            float sm = 0.f;
#pragma unroll
            for (int dy = -1; dy <= 1; ++dy)
#pragma unroll
                for (int dx = -1; dx <= 1; ++dx) {
                    if (dy == 0 && dx == 0) continue;
                    int yy = gy + dy, xx = gx + dx;
                    float pe = 0.f;
                    if (yy >= 0 && yy < 128 && xx >= 0 && xx < 128) pe = s64[yy >> 1][xx >> 1];
                    sm += Ac[dy + 1][dx + 1] * pe;
                }
            s128[pr][pc] = ctr - sm * inv + r5[(size_t)gy * 128 + gx] * inv;
        }
    }
    __syncthreads();
    int R2l = 16 * by - 1, C2l = 16 * bx - 1;
    for (int i = t; i < 324; i += 256) {
        int pr = i / 18, pc = i % 18;
        int gy = R2l + pr, gx = C2l + pc;
        if (gy >= 0 && gy < 256 && gx >= 0 && gx < 256) {
            float ctr = s128[(gy >> 1) - R1][(gx >> 1) - C1];
            float sm = 0.f;
#pragma unroll
            for (int dy = -1; dy <= 1; ++dy)
#pragma unroll
                for (int dx = -1; dx <= 1; ++dx) {
                    if (dy == 0 && dx == 0) continue;
                    int yy = gy + dy, xx = gx + dx;
                    float pe = 0.f;
                    if (yy >= 0 && yy < 256 && xx >= 0 && xx < 256)
                        pe = s128[(yy >> 1) - R1][(xx >> 1) - C1];
                    sm += Ac[dy + 1][dx + 1] * pe;
                }
            s256[pr][pc] = ctr - sm * inv + r4[(size_t)gy * 256 + gx] * inv;
        }
    }
    __syncthreads();
#pragma unroll
    for (int k = 0; k < 4; ++k) {
        int idx = t + 256 * k;
        int y = 32 * by + (idx >> 5), x = 32 * bx + (idx & 31);
        float ctr = s256[(y >> 1) - R2l][(x >> 1) - C2l];
        float sm = 0.f;
#pragma unroll
        for (int dy = -1; dy <= 1; ++dy)
#pragma unroll
            for (int dx = -1; dx <= 1; ++dx) {
                if (dy == 0 && dx == 0) continue;
                int yy = y + dy, xx = x + dx;
                float pe = 0.f;
                if (yy >= 0 && yy < 512 && xx >= 0 && xx < 512)
                    pe = s256[(yy >> 1) - R2l][(xx >> 1) - C2l];
                sm += Ac[dy + 1][dx + 1] * pe;
            }
        e512[(size_t)y * 512 + x] = ctr - sm * inv + r3[(size_t)y * 512 + x] * inv;
    }
}

// ---- fused: e512 -> e1024 (LDS) -> e2048 (regs) -> u update, no u-LDS ----
// Block: 256 thr = 4 waves; u tile 256 cols x 32 rows. Grid (16,128).
template <bool WANTMM>
__global__ __launch_bounds__(256) void final_fused_kernel(
    const float* __restrict__ u, const float* __restrict__ e512,
    const float* __restrict__ r2, const float* __restrict__ r1,
    const float* __restrict__ Ag, float* __restrict__ uo,
    float* __restrict__ partials)
{
    const int n = N;
    int t = threadIdx.x, lane = t & 63, w = t >> 6;
    int bx = blockIdx.x, by = blockIdx.y;
    int x0 = 256 * bx, y0 = 32 * by;
    __shared__ float s512v[6][36];   // e512 rows 4by-1.. (6), cols 32bx-1.. (34 used)
    __shared__ float s1024[10][68];  // e1024 rows 8by-1.. (10), cols 64bx-1.. (66 used)
    float Ac[3][3], inv;
    load_A(Ag, Ac, inv);
    int S5r = 4 * by - 1, S5c = 32 * bx - 1;
    if (t < 216) {
        int pr = t / 36, pc = t - (t / 36) * 36;
        int gy = S5r + pr, gx = S5c + pc;
        float v = 0.f;
        if (pc < 34 && gy >= 0 && gy < 512 && gx >= 0 && gx < 512)
            v = e512[(size_t)gy * 512 + gx];
        s512v[pr][pc] = v;  // oob entries = 0 (zero-padding of e)
    }
    __syncthreads();
    // e1024 patch 10x66 (oob entries = 0)
    int R10 = 8 * by - 1, C10 = 64 * bx - 1;
    for (int i = t; i < 680; i += 256) {
        int pr = i / 68, pc = i - (i / 68) * 68;
        if (pc < 66) {
            int gy = R10 + pr, gx = C10 + pc;
            float val = 0.f;
            if (gy >= 0 && gy < 1024 && gx >= 0 && gx < 1024) {
                float ctr = s512v[(gy >> 1) - S5r][(gx >> 1) - S5c];
                float sm = 0.f;
#pragma unroll
                for (int dy = -1; dy <= 1; ++dy)
#pragma unroll
                    for (int dx = -1; dx <= 1; ++dx) {
                        if (dy == 0 && dx == 0) continue;
                        sm += Ac[dy + 1][dx + 1] *
                              s512v[((gy + dy) >> 1) - S5r][((gx + dx) >> 1) - S5c];
                    }
                val = ctr - sm * inv + r2[(size_t)gy * 1024 + gx] * inv;
            }
            s1024[pr][pc] = val;
        }
    }
    __syncthreads();
    // per-thread e2048: 4 rows x 2 cols (exact r1 footprint, coalesced float2)
    float e2[4][2];
    int EY0 = 16 * by + 4 * w, EX0 = 128 * bx + 2 * lane;
#pragma unroll
    for (int a = 0; a < 4; ++a) {
        int gy = EY0 + a;
        float2 rv = *(const float2*)&r1[(size_t)gy * 2048 + EX0];
#pragma unroll
        for (int b = 0; b < 2; ++b) {
            int gx = EX0 + b;
            float ctr = s1024[(gy >> 1) - R10][(gx >> 1) - C10];
            float sm = 0.f;
#pragma unroll
            for (int dy = -1; dy <= 1; ++dy)
#pragma unroll
                for (int dx = -1; dx <= 1; ++dx) {
                    if (dy == 0 && dx == 0) continue;
                    sm += Ac[dy + 1][dx + 1] *
                          s1024[((gy + dy) >> 1) - R10][((gx + dx) >> 1) - C10];
                }
            float rj = (b == 0) ? rv.x : rv.y;
            e2[a][b] = ctr - sm * inv + rj * inv;
        }
    }
    // u update: preload all 10 rows (MLP), then compute 8 rows
    int yb = y0 + 8 * w;
    int gy0 = yb - 1;
    bool yedge = (gy0 < 0) | (gy0 + 9 >= n);
    int xm = x0 + 4 * lane;
    int colL = max(xm - 1, 0), colR = min(xm + 4, n - 1);
    bool cornL = (xm - 1 < 0), cornR = (xm + 4 >= n);
    float v[10][6];
#pragma unroll
    for (int rr = 0; rr < 10; ++rr)
        load_row6(u, gy0 + rr, xm, colL, colR, cornL, cornR, yedge, v[rr]);

    float mn = 3.402823466e+38f, mx = -3.402823466e+38f;
#pragma unroll
    for (int r = 0; r < 8; ++r) {
        int y = yb + r;
        const float* va = v[r];
        const float* vb = v[r + 1];
        const float* vc = v[r + 2];
        float out[4];
#pragma unroll
        for (int c = 0; c < 4; ++c) {
            float sm = Ac[0][0] * va[c] + Ac[0][1] * va[c + 1] + Ac[0][2] * va[c + 2]
                     + Ac[1][0] * vb[c]                        + Ac[1][2] * vb[c + 2]
                     + Ac[2][0] * vc[c] + Ac[2][1] * vc[c + 1] + Ac[2][2] * vc[c + 2];
            out[c] = vb[c + 1] - e2[r >> 1][c >> 1] - sm * inv;
        }
        *(float4*)&uo[(size_t)y * n + xm] =
            make_float4(out[0], out[1], out[2], out[3]);
        if (WANTMM) {
            mn = fminf(mn, fminf(fminf(out[0], out[1]), fminf(out[2], out[3])));
            mx = fmaxf(mx, fmaxf(fmaxf(out[0], out[1]), fmaxf(out[2], out[3])));
        }
    }
    if (WANTMM) {
#pragma unroll
        for (int off = 32; off > 0; off >>= 1) {
            mn = fminf(mn, __shfl_down(mn, off));
            mx = fmaxf(mx, __shfl_down(mx, off));
        }
        __shared__ float smn[4], smx[4];
        if (lane == 0) { smn[w] = mn; smx[w] = mx; }
        __syncthreads();
        if (t == 0) {
            mn = smn[0]; mx = smx[0];
            for (int wq = 1; wq < 4; ++wq) { mn = fminf(mn, smn[wq]); mx = fmaxf(mx, smx[wq]); }
            int bid = by * 16 + bx;
            partials[2 * bid] = mn;
            partials[2 * bid + 1] = mx;
        }
    }
}

__global__ __launch_bounds__(1024) void minmax_final_kernel(
    const float* __restrict__ partials, float* __restrict__ mm)
{
    float mn = 3.402823466e+38f, mx = -3.402823466e+38f;
    for (int i = threadIdx.x; i < 2048; i += 1024) {
        mn = fminf(mn, partials[2 * i]);
        mx = fmaxf(mx, partials[2 * i + 1]);
    }
#pragma unroll
    for (int off = 32; off > 0; off >>= 1) {
        mn = fminf(mn, __shfl_down(mn, off));
        mx = fmaxf(mx, __shfl_down(mx, off));
    }
    __shared__ float smn[16], smx[16];
    int lane = threadIdx.x & 63, wv = threadIdx.x >> 6;
    if (lane == 0) { smn[wv] = mn; smx[wv] = mx; }
    __syncthreads();
    if (threadIdx.x == 0) {
        mn = smn[0]; mx = smx[0];
        for (int w = 1; w < 16; ++w) { mn = fminf(mn, smn[w]); mx = fmaxf(mx, smx[w]); }
        mm[0] = mn;
        mm[1] = mx;
    }
}

__global__ __launch_bounds__(256) void normalize_kernel(
    float* __restrict__ u, const float* __restrict__ mm)
{
    size_t i = ((size_t)blockIdx.x * 256 + threadIdx.x) * 4;
    float mn = mm[0];
    float sc = 1.0f / (mm[1] - mm[0]);
    float4 v = *(float4*)&u[i];
    v.x = (v.x - mn) * sc;
    v.y = (v.y - mn) * sc;
    v.z = (v.z - mn) * sc;
    v.w = (v.w - mn) * sc;
    *(float4*)&u[i] = v;
}

extern "C" void kernel_launch(void* const* d_in, const int* in_sizes, int n_in,
                              void* d_out, int out_size, void* d_ws, size_t ws_size,
                              hipStream_t stream)
{
    const float* A  = (const float*)d_in[0];
    const float* u0 = (const float*)d_in[1];
    float* uout = (float*)d_out;
    float* ws = (float*)d_ws;

    size_t off = 0;
    float* r1 = ws + off; off += 2048ull * 2048;
    float* r2 = ws + off; off += 1024ull * 1024;
    float* r3 = ws + off; off += 512ull * 512;
    float* r4 = ws + off; off += 256ull * 256;
    float* r5 = ws + off; off += 128ull * 128;
    float* r6 = ws + off; off += 64ull * 64;
    float* r7 = ws + off; off += 32ull * 32;
    float* e5 = ws + off; off += 512ull * 512;
    float* uA = ws + off; off += 4096ull * 4096;
    float* partials = ws + off; off += 4096;
    float* mm = ws + off; off += 2;

    dim3 blk(256);
    for (int it = 0; it < 4; ++it) {
        const float* us = (it == 0) ? u0 : ((it == 2) ? uout : uA);
        float* dst = (it & 1) ? uout : uA;
        smooth_restrict_kernel<<<dim3(16, 128), blk, 0, stream>>>(us, A, r1);
        multirestrict_kernel<<<dim3(32, 32), blk, 0, stream>>>(r1, r2, r3, r4, r5, r6, r7);
        coarse_up_kernel<<<dim3(16, 16), blk, 0, stream>>>(r7, r6, r5, r4, r3, A, e5);
        if (it == 3)
            final_fused_kernel<true><<<dim3(16, 128), blk, 0, stream>>>(us, e5, r2, r1, A, dst, partials);
        else
            final_fused_kernel<false><<<dim3(16, 128), blk, 0, stream>>>(us, e5, r2, r1, A, dst, partials);
    }
    minmax_final_kernel<<<1, 1024, 0, stream>>>(partials, mm);
    normalize_kernel<<<16384, 256, 0, stream>>>(uout, mm);
}

// Round 8
// 281.695 us; speedup vs baseline: 1.5011x; 1.0355x over previous
//
#include <hip/hip_runtime.h>

#define N 4096

__device__ __forceinline__ void load_A(const float* __restrict__ Ag,
                                       float Ac[3][3], float& inv)
{
#pragma unroll
    for (int i = 0; i < 9; ++i) Ac[i / 3][i % 3] = Ag[i];
    inv = 1.0f / Ac[1][1];
    Ac[1][1] = 0.f;
}

__device__ __forceinline__ void make_w44(const float Ac[3][3], float wt[4][4])
{
#pragma unroll
    for (int a = 0; a < 4; ++a)
#pragma unroll
        for (int b = 0; b < 4; ++b) wt[a][b] = 0.f;
#pragma unroll
    for (int r = 0; r < 2; ++r)
#pragma unroll
        for (int c = 0; c < 2; ++c)
#pragma unroll
            for (int i = 0; i < 3; ++i)
#pragma unroll
                for (int j = 0; j < 3; ++j) wt[r + i][c + j] += Ac[i][j];
}

// Branch-free u_bc row segment: lane covers cols xm..xm+3 (aligned float4),
// plus L (xm-1) and R (xm+4) via clamped scalar loads. Corner-zeroing only
// applies in y-edge waves (wave-uniform 'yedge').
__device__ __forceinline__ void load_row6(const float* __restrict__ u,
                                          int gy, int xm, int colL, int colR,
                                          bool cornL, bool cornR, bool yedge,
                                          float v[6])
{
    int cy = min(max(gy, 0), N - 1);
    const float* rowp = &u[(size_t)cy * N];
    float4 m = *(const float4*)&rowp[xm];
    float L = rowp[colL];
    float R = rowp[colR];
    if (yedge) {
        bool oob = (gy < 0) | (gy >= N);
        if (oob & cornL) L = 0.f;
        if (oob & cornR) R = 0.f;
    }
    v[0] = L; v[1] = m.x; v[2] = m.y; v[3] = m.z; v[4] = m.w; v[5] = R;
}

// ---- fused smooth(bc(u)) + restrict + restrict -> r2 (1024^2) directly ----
// Wave: 4 r1 rows x 128 r1 cols (in regs) -> 2 r2 rows x 64 r2 cols. Grid (16,128).
__global__ __launch_bounds__(256) void smooth_restrict2_kernel(
    const float* __restrict__ u, const float* __restrict__ Ag,
    float* __restrict__ r2)
{
    int t = threadIdx.x, lane = t & 63, w = t >> 6;
    int bx = blockIdx.x, by = blockIdx.y;
    int x0 = 256 * bx;
    int Y0 = 16 * by + 4 * w;          // first r1 row of this wave
    int gy0 = 2 * Y0 - 1;
    bool yedge = (gy0 < 0) | (gy0 + 9 >= N);
    float Ac[3][3], inv;
    load_A(Ag, Ac, inv);
    float wt[4][4];
    make_w44(Ac, wt);

    int xm = x0 + 4 * lane;
    int colL = max(xm - 1, 0), colR = min(xm + 4, N - 1);
    bool cornL = (xm - 1 < 0), cornR = (xm + 4 >= N);
    float v[10][6];
#pragma unroll
    for (int rr = 0; rr < 10; ++rr)
        load_row6(u, gy0 + rr, xm, colL, colR, cornL, cornR, yedge, v[rr]);

    float o0[4], o1[4];
#pragma unroll
    for (int q = 0; q < 4; ++q) {
        float a0 = 0.f, a1 = 0.f;
#pragma unroll
        for (int a = 0; a < 4; ++a) {
            const float* vv = v[2 * q + a];
#pragma unroll
            for (int b = 0; b < 4; ++b) {
                a0 += wt[a][b] * vv[b];
                a1 += wt[a][b] * vv[b + 2];
            }
        }
        o0[q] = 0.25f * a0;
        o1[q] = 0.25f * a1;
    }
    // r2 row pair: Y2 = Y0/2 + q', col X2 = 64bx + lane
    int Y2 = Y0 >> 1, X2 = 64 * bx + lane;
#pragma unroll
    for (int qp = 0; qp < 2; ++qp) {
        float val = 0.25f * (o0[2 * qp] + o1[2 * qp] + o0[2 * qp + 1] + o1[2 * qp + 1]);
        r2[(size_t)(Y2 + qp) * 1024 + X2] = val;
    }
}

// ---- one-shot restriction tree: r2 -> r3..r7 ----
// Grid 32x32; block owns 32x32 r2 patch -> 16x16 r3, ... , 1x1 r7.
__global__ __launch_bounds__(256) void multirestrict_kernel(
    const float* __restrict__ r2, float* __restrict__ r3, float* __restrict__ r4,
    float* __restrict__ r5, float* __restrict__ r6, float* __restrict__ r7)
{
    const int n2 = 1024, n3 = 512, n4 = 256, n5 = 128, n6 = 64, n7 = 32;
    int BX = blockIdx.x, BY = blockIdx.y;
    __shared__ float s3[16][17];
    __shared__ float s4[8][9];
    __shared__ float s5[4][5];
    __shared__ float s6[2][3];
    int t = threadIdx.x;
    {
        // 256 threads: each computes one r3 element from a 2x2 of r2
        int y = t >> 4, x = t & 15;
        const float* b0 = &r2[(size_t)(BY * 32 + 2 * y) * n2 + BX * 32 + 2 * x];
        float2 a = *(const float2*)b0;
        float2 b = *(const float2*)(b0 + n2);
        float vv = 0.25f * (a.x + a.y + b.x + b.y);
        r3[(size_t)(BY * 16 + y) * n3 + BX * 16 + x] = vv;
        s3[y][x] = vv;
    }
    __syncthreads();
    if (t < 64) {
        int y = t >> 3, x = t & 7;
        float vv = 0.25f * (s3[2 * y][2 * x] + s3[2 * y][2 * x + 1] +
                            s3[2 * y + 1][2 * x] + s3[2 * y + 1][2 * x + 1]);
        r4[(size_t)(BY * 8 + y) * n4 + BX * 8 + x] = vv;
        s4[y][x] = vv;
    }
    __syncthreads();
    if (t < 16) {
        int y = t >> 2, x = t & 3;
        float vv = 0.25f * (s4[2 * y][2 * x] + s4[2 * y][2 * x + 1] +
                            s4[2 * y + 1][2 * x] + s4[2 * y + 1][2 * x + 1]);
        r5[(size_t)(BY * 4 + y) * n5 + BX * 4 + x] = vv;
        s5[y][x] = vv;
    }
    __syncthreads();
    if (t < 4) {
        int y = t >> 1, x = t & 1;
        float vv = 0.25f * (s5[2 * y][2 * x] + s5[2 * y][2 * x + 1] +
                            s5[2 * y + 1][2 * x] + s5[2 * y + 1][2 * x + 1]);
        r6[(size_t)(BY * 2 + y) * n6 + BX * 2 + x] = vv;
        s6[y][x] = vv;
    }
    __syncthreads();
    if (t == 0) {
        r7[(size_t)BY * n7 + BX] =
            0.25f * (s6[0][0] + s6[0][1] + s6[1][0] + s6[1][1]);
    }
}

// ---- fused coarse up-chain: r7..r3 -> e@512 ----
__global__ __launch_bounds__(256) void coarse_up_kernel(
    const float* __restrict__ r7, const float* __restrict__ r6,
    const float* __restrict__ r5, const float* __restrict__ r4,
    const float* __restrict__ r3, const float* __restrict__ Ag,
    float* __restrict__ e512)
{
    int bx = blockIdx.x, by = blockIdx.y;  // 16x16 grid, 32x32 of e512 each
    int t = threadIdx.x;
    __shared__ float s7[32][33];
    __shared__ float s64[64][65];
    __shared__ float s128[11][12];
    __shared__ float s256[18][19];
    float Ac[3][3], inv;
    load_A(Ag, Ac, inv);
    for (int i = t; i < 1024; i += 256) s7[i >> 5][i & 31] = r7[i] * inv;
    __syncthreads();
    for (int i = t; i < 4096; i += 256) {
        int y = i >> 6, x = i & 63;
        float ctr = s7[y >> 1][x >> 1];
        float sm = 0.f;
#pragma unroll
        for (int dy = -1; dy <= 1; ++dy)
#pragma unroll
            for (int dx = -1; dx <= 1; ++dx) {
                if (dy == 0 && dx == 0) continue;
                int yy = y + dy, xx = x + dx;
                float pe = 0.f;
                if (yy >= 0 && yy < 64 && xx >= 0 && xx < 64) pe = s7[yy >> 1][xx >> 1];
                sm += Ac[dy + 1][dx + 1] * pe;
            }
        s64[y][x] = ctr - sm * inv + r6[i] * inv;
    }
    __syncthreads();
    int R1 = 8 * by - 2, C1 = 8 * bx - 2;
    if (t < 121) {
        int pr = t / 11, pc = t % 11;
        int gy = R1 + pr, gx = C1 + pc;
        if (gy >= 0 && gy < 128 && gx >= 0 && gx < 128) {
            float ctr = s64[gy >> 1][gx >> 1];
            float sm = 0.f;
#pragma unroll
            for (int dy = -1; dy <= 1; ++dy)
#pragma unroll
                for (int dx = -1; dx <= 1; ++dx) {
                    if (dy == 0 && dx == 0) continue;
                    int yy = gy + dy, xx = gx + dx;
                    float pe = 0.f;
                    if (yy >= 0 && yy < 128 && xx >= 0 && xx < 128) pe = s64[yy >> 1][xx >> 1];
                    sm += Ac[dy + 1][dx + 1] * pe;
                }
            s128[pr][pc] = ctr - sm * inv + r5[(size_t)gy * 128 + gx] * inv;
        }
    }
    __syncthreads();
    int R2l = 16 * by - 1, C2l = 16 * bx - 1;
    for (int i = t; i < 324; i += 256) {
        int pr = i / 18, pc = i % 18;
        int gy = R2l + pr, gx = C2l + pc;
        if (gy >= 0 && gy < 256 && gx >= 0 && gx < 256) {
            float ctr = s128[(gy >> 1) - R1][(gx >> 1) - C1];
            float sm = 0.f;
#pragma unroll
            for (int dy = -1; dy <= 1; ++dy)
#pragma unroll
                for (int dx = -1; dx <= 1; ++dx) {
                    if (dy == 0 && dx == 0) continue;
                    int yy = gy + dy, xx = gx + dx;
                    float pe = 0.f;
                    if (yy >= 0 && yy < 256 && xx >= 0 && xx < 256)
                        pe = s128[(yy >> 1) - R1][(xx >> 1) - C1];
                    sm += Ac[dy + 1][dx + 1] * pe;
                }
            s256[pr][pc] = ctr - sm * inv + r4[(size_t)gy * 256 + gx] * inv;
        }
    }
    __syncthreads();
#pragma unroll
    for (int k = 0; k < 4; ++k) {
        int idx = t + 256 * k;
        int y = 32 * by + (idx >> 5), x = 32 * bx + (idx & 31);
        float ctr = s256[(y >> 1) - R2l][(x >> 1) - C2l];
        float sm = 0.f;
#pragma unroll
        for (int dy = -1; dy <= 1; ++dy)
#pragma unroll
            for (int dx = -1; dx <= 1; ++dx) {
                if (dy == 0 && dx == 0) continue;
                int yy = y + dy, xx = x + dx;
                float pe = 0.f;
                if (yy >= 0 && yy < 512 && xx >= 0 && xx < 512)
                    pe = s256[(yy >> 1) - R2l][(xx >> 1) - C2l];
                sm += Ac[dy + 1][dx + 1] * pe;
            }
        e512[(size_t)y * 512 + x] = ctr - sm * inv + r3[(size_t)y * 512 + x] * inv;
    }
}

// ---- fused: e512 -> e1024 (LDS) -> e2048 (regs, r1 recomputed) -> u update ----
// Block: 256 thr = 4 waves; u tile 256 cols x 32 rows. Grid (16,128).
template <bool WANTMM>
__global__ __launch_bounds__(256) void final_fused_kernel(
    const float* __restrict__ u, const float* __restrict__ e512,
    const float* __restrict__ r2, const float* __restrict__ Ag,
    float* __restrict__ uo, float* __restrict__ partials)
{
    const int n = N;
    int t = threadIdx.x, lane = t & 63, w = t >> 6;
    int bx = blockIdx.x, by = blockIdx.y;
    int x0 = 256 * bx, y0 = 32 * by;
    __shared__ float s512v[6][36];   // e512 rows 4by-1.. (6), cols 32bx-1.. (34 used)
    __shared__ float s1024[10][68];  // e1024 rows 8by-1.. (10), cols 64bx-1.. (66 used)
    float Ac[3][3], inv;
    load_A(Ag, Ac, inv);
    float wt[4][4];
    make_w44(Ac, wt);

    // issue u row loads early for MLP; consumed after the e-chain
    int yb = y0 + 8 * w;
    int gy0 = yb - 1;
    bool yedge = (gy0 < 0) | (gy0 + 9 >= n);
    int xm = x0 + 4 * lane;
    int colL = max(xm - 1, 0), colR = min(xm + 4, n - 1);
    bool cornL = (xm - 1 < 0), cornR = (xm + 4 >= n);
    float v[10][6];
#pragma unroll
    for (int rr = 0; rr < 10; ++rr)
        load_row6(u, gy0 + rr, xm, colL, colR, cornL, cornR, yedge, v[rr]);

    int S5r = 4 * by - 1, S5c = 32 * bx - 1;
    if (t < 216) {
        int pr = t / 36, pc = t - (t / 36) * 36;
        int gy = S5r + pr, gx = S5c + pc;
        float vv = 0.f;
        if (pc < 34 && gy >= 0 && gy < 512 && gx >= 0 && gx < 512)
            vv = e512[(size_t)gy * 512 + gx];
        s512v[pr][pc] = vv;  // oob entries = 0 (zero-padding of e)
    }
    __syncthreads();
    // e1024 patch 10x66 (oob entries = 0)
    int R10 = 8 * by - 1, C10 = 64 * bx - 1;
    for (int i = t; i < 680; i += 256) {
        int pr = i / 68, pc = i - (i / 68) * 68;
        if (pc < 66) {
            int gy = R10 + pr, gx = C10 + pc;
            float val = 0.f;
            if (gy >= 0 && gy < 1024 && gx >= 0 && gx < 1024) {
                float ctr = s512v[(gy >> 1) - S5r][(gx >> 1) - S5c];
                float sm = 0.f;
#pragma unroll
                for (int dy = -1; dy <= 1; ++dy)
#pragma unroll
                    for (int dx = -1; dx <= 1; ++dx) {
                        if (dy == 0 && dx == 0) continue;
                        sm += Ac[dy + 1][dx + 1] *
                              s512v[((gy + dy) >> 1) - S5r][((gx + dx) >> 1) - S5c];
                    }
                val = ctr - sm * inv + r2[(size_t)gy * 1024 + gx] * inv;
            }
            s1024[pr][pc] = val;
        }
    }
    __syncthreads();
    // per-thread e2048: 4 rows x 2 cols; r1 recomputed in regs from v[][]
    float e2[4][2];
    int EY0 = 16 * by + 4 * w, EX0 = 128 * bx + 2 * lane;
#pragma unroll
    for (int a = 0; a < 4; ++a) {
        int gy = EY0 + a;
        // r1 values at (gy, EX0) and (gy, EX0+1): same math as smooth_restrict
        float a0 = 0.f, a1 = 0.f;
#pragma unroll
        for (int i = 0; i < 4; ++i) {
            const float* vv = v[2 * a + i];
#pragma unroll
            for (int j = 0; j < 4; ++j) {
                a0 += wt[i][j] * vv[j];
                a1 += wt[i][j] * vv[j + 2];
            }
        }
        float r1v[2] = {0.25f * a0, 0.25f * a1};
#pragma unroll
        for (int b = 0; b < 2; ++b) {
            int gx = EX0 + b;
            float ctr = s1024[(gy >> 1) - R10][(gx >> 1) - C10];
            float sm = 0.f;
#pragma unroll
            for (int dy = -1; dy <= 1; ++dy)
#pragma unroll
                for (int dx = -1; dx <= 1; ++dx) {
                    if (dy == 0 && dx == 0) continue;
                    sm += Ac[dy + 1][dx + 1] *
                          s1024[((gy + dy) >> 1) - R10][((gx + dx) >> 1) - C10];
                }
            e2[a][b] = ctr - sm * inv + r1v[b] * inv;
        }
    }
    // u update: 8 rows from the preloaded window
    float mn = 3.402823466e+38f, mx = -3.402823466e+38f;
#pragma unroll
    for (int r = 0; r < 8; ++r) {
        int y = yb + r;
        const float* va = v[r];
        const float* vb = v[r + 1];
        const float* vc = v[r + 2];
        float out[4];
#pragma unroll
        for (int c = 0; c < 4; ++c) {
            float sm = Ac[0][0] * va[c] + Ac[0][1] * va[c + 1] + Ac[0][2] * va[c + 2]
                     + Ac[1][0] * vb[c]                        + Ac[1][2] * vb[c + 2]
                     + Ac[2][0] * vc[c] + Ac[2][1] * vc[c + 1] + Ac[2][2] * vc[c + 2];
            out[c] = vb[c + 1] - e2[r >> 1][c >> 1] - sm * inv;
        }
        *(float4*)&uo[(size_t)y * n + xm] =
            make_float4(out[0], out[1], out[2], out[3]);
        if (WANTMM) {
            mn = fminf(mn, fminf(fminf(out[0], out[1]), fminf(out[2], out[3])));
            mx = fmaxf(mx, fmaxf(fmaxf(out[0], out[1]), fmaxf(out[2], out[3])));
        }
    }
    if (WANTMM) {
#pragma unroll
        for (int off = 32; off > 0; off >>= 1) {
            mn = fminf(mn, __shfl_down(mn, off));
            mx = fmaxf(mx, __shfl_down(mx, off));
        }
        __shared__ float smn[4], smx[4];
        if (lane == 0) { smn[w] = mn; smx[w] = mx; }
        __syncthreads();
        if (t == 0) {
            mn = smn[0]; mx = smx[0];
            for (int wq = 1; wq < 4; ++wq) { mn = fminf(mn, smn[wq]); mx = fmaxf(mx, smx[wq]); }
            int bid = by * 16 + bx;
            partials[2 * bid] = mn;
            partials[2 * bid + 1] = mx;
        }
    }
}

__global__ __launch_bounds__(1024) void minmax_final_kernel(
    const float* __restrict__ partials, float* __restrict__ mm)
{
    float mn = 3.402823466e+38f, mx = -3.402823466e+38f;
    for (int i = threadIdx.x; i < 2048; i += 1024) {
        mn = fminf(mn, partials[2 * i]);
        mx = fmaxf(mx, partials[2 * i + 1]);
    }
#pragma unroll
    for (int off = 32; off > 0; off >>= 1) {
        mn = fminf(mn, __shfl_down(mn, off));
        mx = fmaxf(mx, __shfl_down(mx, off));
    }
    __shared__ float smn[16], smx[16];
    int lane = threadIdx.x & 63, wv = threadIdx.x >> 6;
    if (lane == 0) { smn[wv] = mn; smx[wv] = mx; }
    __syncthreads();
    if (threadIdx.x == 0) {
        mn = smn[0]; mx = smx[0];
        for (int w = 1; w < 16; ++w) { mn = fminf(mn, smn[w]); mx = fmaxf(mx, smx[w]); }
        mm[0] = mn;
        mm[1] = mx;
    }
}

__global__ __launch_bounds__(256) void normalize_kernel(
    float* __restrict__ u, const float* __restrict__ mm)
{
    size_t i = ((size_t)blockIdx.x * 256 + threadIdx.x) * 4;
    float mn = mm[0];
    float sc = 1.0f / (mm[1] - mm[0]);
    float4 v = *(float4*)&u[i];
    v.x = (v.x - mn) * sc;
    v.y = (v.y - mn) * sc;
    v.z = (v.z - mn) * sc;
    v.w = (v.w - mn) * sc;
    *(float4*)&u[i] = v;
}

extern "C" void kernel_launch(void* const* d_in, const int* in_sizes, int n_in,
                              void* d_out, int out_size, void* d_ws, size_t ws_size,
                              hipStream_t stream)
{
    const float* A  = (const float*)d_in[0];
    const float* u0 = (const float*)d_in[1];
    float* uout = (float*)d_out;
    float* ws = (float*)d_ws;

    size_t off = 0;
    float* r2 = ws + off; off += 1024ull * 1024;
    float* r3 = ws + off; off += 512ull * 512;
    float* r4 = ws + off; off += 256ull * 256;
    float* r5 = ws + off; off += 128ull * 128;
    float* r6 = ws + off; off += 64ull * 64;
    float* r7 = ws + off; off += 32ull * 32;
    float* e5 = ws + off; off += 512ull * 512;
    float* uA = ws + off; off += 4096ull * 4096;
    float* partials = ws + off; off += 4096;
    float* mm = ws + off; off += 2;

    dim3 blk(256);
    for (int it = 0; it < 4; ++it) {
        const float* us = (it == 0) ? u0 : ((it == 2) ? uout : uA);
        float* dst = (it & 1) ? uout : uA;
        smooth_restrict2_kernel<<<dim3(16, 128), blk, 0, stream>>>(us, A, r2);
        multirestrict_kernel<<<dim3(32, 32), blk, 0, stream>>>(r2, r3, r4, r5, r6, r7);
        coarse_up_kernel<<<dim3(16, 16), blk, 0, stream>>>(r7, r6, r5, r4, r3, A, e5);
        if (it == 3)
            final_fused_kernel<true><<<dim3(16, 128), blk, 0, stream>>>(us, e5, r2, A, dst, partials);
        else
            final_fused_kernel<false><<<dim3(16, 128), blk, 0, stream>>>(us, e5, r2, A, dst, partials);
    }
    minmax_final_kernel<<<1, 1024, 0, stream>>>(partials, mm);
    normalize_kernel<<<16384, 256, 0, stream>>>(uout, mm);
}